// Round 2
// baseline (145.534 us; speedup 1.0000x reference)
//
#include <hip/hip_runtime.h>
#include <math.h>

#define NCLS 80           // background label
#define KDIM 128
#define INV_T 5.0f        // 1/TEMPERATURE

typedef __attribute__((ext_vector_type(4))) float  floatx4;
typedef __attribute__((ext_vector_type(8))) short  short8;

__device__ inline unsigned short f2bf(float x) {      // fp32 -> bf16 RNE
    unsigned int u = __float_as_uint(x);
    u += 0x7fffu + ((u >> 16) & 1u);
    return (unsigned short)(u >> 16);
}
__device__ inline short8 pack8(float4 a, float4 b) {
    short8 o;
    o[0] = (short)f2bf(a.x); o[1] = (short)f2bf(a.y);
    o[2] = (short)f2bf(a.z); o[3] = (short)f2bf(a.w);
    o[4] = (short)f2bf(b.x); o[5] = (short)f2bf(b.y);
    o[6] = (short)f2bf(b.z); o[7] = (short)f2bf(b.w);
    return o;
}
// async 16B global->LDS; LDS dest is wave-uniform base + lane*16
__device__ inline void g2lds16(const void* g, void* l) {
    __builtin_amdgcn_global_load_lds(
        (const __attribute__((address_space(1))) void*)g,
        (__attribute__((address_space(3))) void*)l, 16, 0, 0);
}

// ---------------- setup: compact novel indices, counts, zero accumulators,
// convert feats/protos to bf16 (Fb has zero row M, Pb zero-padded to 128),
// and build Fsum = sum of novel feature rows, Psum = sum of proto rows -------
__global__ __launch_bounds__(256) void setup_kernel(
    const float* __restrict__ feats, const int* __restrict__ labels,
    const float* __restrict__ protos, int M, int B,
    int* __restrict__ novel_idx, int* __restrict__ counters,
    float* __restrict__ S1, float* __restrict__ EK,
    float* __restrict__ Fsum, float* __restrict__ Psum,
    float* __restrict__ out,
    unsigned short* __restrict__ Fb, unsigned short* __restrict__ Pb)
{
    __shared__ float sred[256][8];
    const int tid = threadIdx.x;
    const int i = blockIdx.x * 256 + tid;
    const int T = gridDim.x * 256;                 // 65536 (multiple of 16)
    if (i == 0) out[0] = 0.f;
    if (i < M) {
        S1[i] = 0.f; EK[i] = 0.f;
        int lab = labels[i];
        bool fg  = (lab != NCLS);
        bool isb = fg && (lab >= 0) && (lab < B);
        bool isn = fg && !isb;
        if (isn) { int p = atomicAdd(&counters[0], 1); novel_idx[p] = i; }
        if (fg)  atomicAdd(&counters[1], 1);   // numel
        if (isb) atomicAdd(&counters[2], 1);   // n_base
    }

    // feats -> bf16 rows 0..M-1 + zero row M; fold novel-row sum into the pass.
    // Grid-stride keeps chunk-in-row c = i&15 constant per thread.
    float4 fa0 = make_float4(0.f, 0.f, 0.f, 0.f);
    float4 fa1 = make_float4(0.f, 0.f, 0.f, 0.f);
    const int nch = (M + 1) * (KDIM / 8);          // 16-byte chunks
    for (int ch = i; ch < nch; ch += T) {
        short8 o = (short8)0;
        if (ch < M * (KDIM / 8)) {
            const float4* f4 = (const float4*)feats + (size_t)ch * 2;
            float4 v0 = f4[0], v1 = f4[1];
            o = pack8(v0, v1);
            int lab = labels[ch >> 4];
            bool isn = (lab != NCLS) && !((lab >= 0) && (lab < B));
            if (isn) {
                fa0.x += v0.x; fa0.y += v0.y; fa0.z += v0.z; fa0.w += v0.w;
                fa1.x += v1.x; fa1.y += v1.y; fa1.z += v1.z; fa1.w += v1.w;
            }
        }
        *(short8*)&Fb[(size_t)ch * 8] = o;
    }
    // block-level tree reduce of the 8-dim partials (threads with equal tid&15
    // own the same dim group; stride 16 preserves the group)
    sred[tid][0] = fa0.x; sred[tid][1] = fa0.y; sred[tid][2] = fa0.z; sred[tid][3] = fa0.w;
    sred[tid][4] = fa1.x; sred[tid][5] = fa1.y; sred[tid][6] = fa1.z; sred[tid][7] = fa1.w;
    __syncthreads();
    for (int s = 128; s >= 16; s >>= 1) {
        if (tid < s) {
            #pragma unroll
            for (int j = 0; j < 8; ++j) sred[tid][j] += sred[tid + s][j];
        }
        __syncthreads();
    }
    if (tid < 16) {
        #pragma unroll
        for (int j = 0; j < 8; ++j) atomicAdd(&Fsum[tid * 8 + j], sred[tid][j]);
    }

    // protos -> bf16 zero-padded to 128 rows; accumulate Psum
    if (i < 128 * (KDIM / 8)) {
        int r = i >> 4, c = i & 15;
        short8 o = (short8)0;
        if (r < B) {
            const float4* p4 = (const float4*)protos + (size_t)i * 2;
            float4 v0 = p4[0], v1 = p4[1];
            o = pack8(v0, v1);
            atomicAdd(&Psum[c * 8 + 0], v0.x); atomicAdd(&Psum[c * 8 + 1], v0.y);
            atomicAdd(&Psum[c * 8 + 2], v0.z); atomicAdd(&Psum[c * 8 + 3], v0.w);
            atomicAdd(&Psum[c * 8 + 4], v1.x); atomicAdd(&Psum[c * 8 + 5], v1.y);
            atomicAdd(&Psum[c * 8 + 6], v1.z); atomicAdd(&Psum[c * 8 + 7], v1.w);
        }
        *(short8*)&Pb[(size_t)i * 8] = o;
    }
}

// ---------------- shuffle-reduce + atomic flush of a run's exp-sums ----------
__device__ inline void flush_se(float se16[4][4], float* dest, int row0,
                                int wrow, int quad, int lr, int M)
{
    #pragma unroll
    for (int r = 0; r < 4; ++r) {
        #pragma unroll
        for (int reg = 0; reg < 4; ++reg) {
            float v = se16[r][reg];
            #pragma unroll
            for (int off = 1; off < 16; off <<= 1) v += __shfl_xor(v, off);
            if (lr == 0) {
                int irow = row0 + wrow + r * 16 + quad * 4 + reg;
                if (irow < M) atomicAdd(&dest[irow], v);
            }
        }
    }
}

// ---------------- MFMA GEMM: exp-sums over novel/proto column tiles ----------
// Balanced device-side partition of the rt-major tile list (width = ntiles+1)
// over a fixed grid; A panel staged once per rt-run; epilogue accumulates
// per-lane exp-sums across the run and flushes once per destination run.
__global__ __launch_bounds__(256, 2) void gemm_kernel(
    const unsigned short* __restrict__ Fb, const unsigned short* __restrict__ Pb,
    const int* __restrict__ novel_idx, const int* __restrict__ counters,
    int M, int B,
    float* __restrict__ S1, float* __restrict__ EK)
{
    __shared__ unsigned short As[128 * 128];   // 32 KiB, linear (swizzled chunks)
    __shared__ unsigned short Bs[128 * 128];   // 32 KiB
    __shared__ int nidx[128];

    const int Nn = counters[0];
    const int ntiles = (Nn + 127) >> 7;        // novel col tiles
    const int width = ntiles + 1;              // + proto tile
    const int rtc = (M + 127) >> 7;            // row tiles
    const long total = (long)rtc * width;
    const int G = gridDim.x, b = blockIdx.x;
    const int t0 = (int)(total * b / G);
    const int t1 = (int)(total * (b + 1) / G);
    if (t0 >= t1) return;

    const int tid = threadIdx.x;
    const int wbase = tid & ~63;               // wave-uniform thread base
    const int wave = tid >> 6, lane = tid & 63;
    const int lr = lane & 15, quad = lane >> 4;
    const int wrow = (wave >> 1) * 64, wcol = (wave & 1) * 64;

    float se16[4][4];
    float* pend = nullptr;
    int pend_row0 = 0;
    int cur_rt = -1;
    bool first = true;

    for (int t = t0; t < t1; ++t) {
        const int rt = t / width, ct = t - rt * width;
        const bool isp = (ct == ntiles);
        const int row0 = rt * 128;
        float* dest = isp ? EK : S1;

        if (dest != pend || row0 != pend_row0) {       // block-uniform
            if (pend) flush_se(se16, pend, pend_row0, wrow, quad, lr, M);
            #pragma unroll
            for (int r = 0; r < 4; ++r)
                #pragma unroll
                for (int g = 0; g < 4; ++g) se16[r][g] = 0.f;
            pend = dest; pend_row0 = row0;
        }

        if (!first) __syncthreads();           // readers of prev tile done
        first = false;

        if (rt != cur_rt) {                    // stage A once per rt-run
            cur_rt = rt;
            const unsigned short* a0 = Fb + (size_t)row0 * KDIM;
            #pragma unroll
            for (int p = 0; p < 8; ++p) {
                int Lc = p * 256 + tid;
                int r = Lc >> 4, c = Lc & 15;
                int cs = c ^ (r & 15);         // source-side XOR swizzle
                g2lds16(a0 + (size_t)r * KDIM + cs * 8,
                        As + (size_t)(p * 256 + wbase) * 8);
            }
        }
        #pragma unroll
        for (int p = 0; p < 8; ++p) {          // stage B (gathered / protos)
            int Lc = p * 256 + tid;
            int r = Lc >> 4, c = Lc & 15;
            int cs = c ^ (r & 15);
            const unsigned short* base; int nid;
            if (isp) { base = Pb; nid = r; }              // Pb zero-padded
            else {
                base = Fb;
                int jg = ct * 128 + r;
                nid = (jg < Nn) ? novel_idx[jg] : M;      // M = zero row
            }
            g2lds16(base + (size_t)nid * KDIM + cs * 8,
                    Bs + (size_t)(p * 256 + wbase) * 8);
        }
        if (tid < 128) {
            int nid = -1;
            if (isp) { if (tid < B) nid = tid; }
            else { int jg = ct * 128 + tid; if (jg < Nn) nid = novel_idx[jg]; }
            nidx[tid] = nid;
        }
        __syncthreads();                       // drains vmcnt (async LDS loads)

        floatx4 acc[4][4];
        #pragma unroll
        for (int r = 0; r < 4; ++r)
            #pragma unroll
            for (int c = 0; c < 4; ++c)
                acc[r][c] = (floatx4){0.f, 0.f, 0.f, 0.f};

        #pragma unroll
        for (int ks = 0; ks < 4; ++ks) {       // swizzled ds_read_b128
            short8 a[4], bfr[4];
            #pragma unroll
            for (int r = 0; r < 4; ++r) {
                int row = wrow + r * 16 + lr;
                int phys = (ks * 4 + quad) ^ lr;
                a[r] = *(const short8*)&As[row * KDIM + phys * 8];
            }
            #pragma unroll
            for (int c = 0; c < 4; ++c) {
                int row = wcol + c * 16 + lr;
                int phys = (ks * 4 + quad) ^ lr;
                bfr[c] = *(const short8*)&Bs[row * KDIM + phys * 8];
            }
            #pragma unroll
            for (int r = 0; r < 4; ++r)
                #pragma unroll
                for (int c = 0; c < 4; ++c)
                    acc[r][c] = __builtin_amdgcn_mfma_f32_16x16x32_bf16(
                        a[r], bfr[c], acc[r][c], 0, 0, 0);
        }

        int ncol[4];
        #pragma unroll
        for (int c = 0; c < 4; ++c) ncol[c] = nidx[wcol + c * 16 + lr];
        #pragma unroll
        for (int r = 0; r < 4; ++r) {
            int ibase = row0 + wrow + r * 16 + quad * 4;
            #pragma unroll
            for (int reg = 0; reg < 4; ++reg) {
                int irow = ibase + reg;        // C/D: col=lane&15, row=quad*4+reg
                float se = 0.f;
                #pragma unroll
                for (int c = 0; c < 4; ++c) {
                    float sim = acc[r][c][reg] * INV_T;
                    bool valid = (ncol[c] >= 0) && (isp || ncol[c] != irow);
                    if (valid) se += __expf(sim);
                }
                se16[r][reg] += se;
            }
        }
    }
    flush_se(se16, pend, pend_row0, wrow, quad, lr, M);
}

// ---------------- finalize: rank-1 raw sums (fp32 exact) + per-row losses ----
__global__ __launch_bounds__(256) void finalize_kernel(
    const float* __restrict__ feats, const float* __restrict__ protos,
    const int* __restrict__ labels,
    const float* __restrict__ S1, const float* __restrict__ EK,
    const float* __restrict__ Fsum, const float* __restrict__ Psum,
    const int* __restrict__ counters, int M, int B, float* __restrict__ out)
{
    __shared__ float part[16];
    const int tid  = threadIdx.x;
    const int rloc = tid >> 4;
    const int q    = tid & 15;
    const int row  = blockIdx.x * 16 + rloc;
    const int rs   = min(row, M - 1);

    const int Nn = counters[0], numel = counters[1], nbase = counters[2];

    int lab = labels[rs];
    bool fg  = (lab != NCLS);
    bool isb = fg && (lab >= 0) && (lab < B);
    bool isn = fg && !isb;
    int  sl  = min(max(lab, 0), B - 1);

    // fp32 dots: f.proto[sl], f.Fsum, f.Psum, f.f  (16 lanes x 8 elems)
    float dp = 0.f, dfs = 0.f, dps = 0.f, dsf = 0.f;
    #pragma unroll
    for (int j = 0; j < 8; ++j) {
        int k = q + j * 16;
        float f = feats[(size_t)rs * KDIM + k];
        dp  += f * protos[(size_t)sl * KDIM + k];
        dfs += f * Fsum[k];
        dps += f * Psum[k];
        dsf += f * f;
    }
    #pragma unroll
    for (int off = 1; off < 16; off <<= 1) {
        dp  += __shfl_xor(dp, off);
        dfs += __shfl_xor(dfs, off);
        dps += __shfl_xor(dps, off);
        dsf += __shfl_xor(dsf, off);
    }

    if (q == 0) {
        float loss = 0.f;
        if (row < M) {
            if (isn && Nn > 1) {
                float cnt = (float)(Nn - 1);
                float T1  = (dfs - dsf) * INV_T;       // sum sim over novel j!=i
                float PKr = dps * INV_T;               // sum raw pk
                float dn  = S1[rs] + PKr;
                loss = -(T1 - cnt * logf(dn)) / cnt;
            } else if (isb && nbase > 0) {
                float pi = dp * INV_T;
                float db = S1[rs] + EK[rs];
                loss = -(pi - logf(db));
            }
        }
        part[rloc] = loss;
    }
    __syncthreads();
    if (tid == 0) {
        float s = 0.f;
        #pragma unroll
        for (int r = 0; r < 16; ++r) s += part[r];
        atomicAdd(out, s / (float)numel);
    }
}

extern "C" void kernel_launch(void* const* d_in, const int* in_sizes, int n_in,
                              void* d_out, int out_size, void* d_ws, size_t ws_size,
                              hipStream_t stream)
{
    const float* feats  = (const float*)d_in[0];
    const int*   labels = (const int*)d_in[1];
    const float* protos = (const float*)d_in[2];
    // d_in[3] proto_labels == arange(B); base membership == (label < B)

    const int M = in_sizes[1];
    const int B = in_sizes[3];

    char* ws = (char*)d_ws;
    int*   counters = (int*)ws;                   // [0,64)
    float* Fsum = (float*)(ws + 256);             // 128 floats
    float* Psum = (float*)(ws + 768);             // 128 floats
    float* S1  = (float*)(ws + 2048);
    float* EK  = S1 + M;
    int*   novel_idx = (int*)(EK + M);            // M ints
    unsigned short* Fb = (unsigned short*)(novel_idx + M);   // (M+1) x 128 bf16
    unsigned short* Pb = Fb + (size_t)(M + 1) * KDIM;        // 128 x 128 bf16

    hipMemsetAsync(ws, 0, 2048, stream);          // counters + Fsum + Psum

    setup_kernel<<<256, 256, 0, stream>>>(
        feats, labels, protos, M, B, novel_idx, counters,
        S1, EK, Fsum, Psum, (float*)d_out, Fb, Pb);

    gemm_kernel<<<512, 256, 0, stream>>>(
        Fb, Pb, novel_idx, counters, M, B, S1, EK);

    finalize_kernel<<<(M + 15) / 16, 256, 0, stream>>>(
        feats, protos, labels, S1, EK, Fsum, Psum, counters, M, B, (float*)d_out);
}

// Round 3
// 99.119 us; speedup vs baseline: 1.4683x; 1.4683x over previous
//
#include <hip/hip_runtime.h>
#include <math.h>

#define NCLS 80           // background label
#define KDIM 128
#define INV_T 5.0f        // 1/TEMPERATURE

typedef __attribute__((ext_vector_type(4))) float  floatx4;
typedef __attribute__((ext_vector_type(8))) short  short8;

__device__ inline unsigned short f2bf(float x) {      // fp32 -> bf16 RNE
    unsigned int u = __float_as_uint(x);
    u += 0x7fffu + ((u >> 16) & 1u);
    return (unsigned short)(u >> 16);
}
__device__ inline short8 pack8(float4 a, float4 b) {
    short8 o;
    o[0] = (short)f2bf(a.x); o[1] = (short)f2bf(a.y);
    o[2] = (short)f2bf(a.z); o[3] = (short)f2bf(a.w);
    o[4] = (short)f2bf(b.x); o[5] = (short)f2bf(b.y);
    o[6] = (short)f2bf(b.z); o[7] = (short)f2bf(b.w);
    return o;
}
// async 16B global->LDS; LDS dest is wave-uniform base + lane*16
__device__ inline void g2lds16(const void* g, void* l) {
    __builtin_amdgcn_global_load_lds(
        (const __attribute__((address_space(1))) void*)g,
        (__attribute__((address_space(3))) void*)l, 16, 0, 0);
}

// ---------------- setup: compact novel indices, counts, zero accumulators,
// convert feats -> bf16 (Fb, + zero row M), protos -> bf16 (Pb, padded to 128).
// Lean streaming pass: no cross-block float atomics, no LDS reductions. ------
__global__ __launch_bounds__(256) void setup_kernel(
    const float* __restrict__ feats, const int* __restrict__ labels,
    const float* __restrict__ protos, int M, int B,
    int* __restrict__ novel_idx, int* __restrict__ counters,
    float* __restrict__ S1, float* __restrict__ T1,
    float* __restrict__ PKr, float* __restrict__ EK, float* __restrict__ out,
    unsigned short* __restrict__ Fb, unsigned short* __restrict__ Pb)
{
    const int i = blockIdx.x * 256 + threadIdx.x;
    const int T = gridDim.x * 256;
    if (i == 0) out[0] = 0.f;
    if (i < M) {
        S1[i] = 0.f; T1[i] = 0.f; PKr[i] = 0.f; EK[i] = 0.f;
        int lab = labels[i];
        bool fg  = (lab != NCLS);
        bool isb = fg && (lab >= 0) && (lab < B);
        bool isn = fg && !isb;
        if (isn) { int p = atomicAdd(&counters[0], 1); novel_idx[p] = i; }
        if (fg)  atomicAdd(&counters[1], 1);   // numel
        if (isb) atomicAdd(&counters[2], 1);   // n_base
    }
    // feats -> bf16 rows 0..M-1, plus zero row M (gather target for invalid cols)
    const int nch = (M + 1) * (KDIM / 8);      // 16-byte chunks
    for (int ch = i; ch < nch; ch += T) {
        short8 o = (short8)0;
        if (ch < M * (KDIM / 8)) {
            const float4* f4 = (const float4*)feats + (size_t)ch * 2;
            o = pack8(f4[0], f4[1]);
        }
        *(short8*)&Fb[(size_t)ch * 8] = o;
    }
    // protos -> bf16, zero-padded to 128 rows
    if (i < 128 * (KDIM / 8)) {
        int r = i >> 4;
        short8 o = (short8)0;
        if (r < B) {
            const float4* p4 = (const float4*)protos + (size_t)i * 2;
            o = pack8(p4[0], p4[1]);
        }
        *(short8*)&Pb[(size_t)i * 8] = o;
    }
}

// ---- shuffle-reduce + atomic flush of a run's (exp-sum, raw-sum) pairs ------
__device__ inline void flush_run(float se16[4][4], float sr16[4][4],
                                 float* dE, float* dR, int row0,
                                 int wrow, int quad, int lr, int M)
{
    #pragma unroll
    for (int r = 0; r < 4; ++r) {
        #pragma unroll
        for (int reg = 0; reg < 4; ++reg) {
            float ve = se16[r][reg], vr = sr16[r][reg];
            #pragma unroll
            for (int off = 1; off < 16; off <<= 1) {
                ve += __shfl_xor(ve, off);
                vr += __shfl_xor(vr, off);
            }
            if (lr == 0) {
                int irow = row0 + wrow + r * 16 + quad * 4 + reg;
                if (irow < M) { atomicAdd(&dE[irow], ve); atomicAdd(&dR[irow], vr); }
            }
        }
    }
}

// ---------------- MFMA GEMM: exp-sums and raw-sums over novel/proto cols -----
// Balanced device-side partition of the rt-major tile list (width = ntiles+1)
// over a fixed grid; A panel staged once per rt-run; epilogue accumulates
// per-lane (se,sr) across the run and flushes once per destination run.
__global__ __launch_bounds__(256, 2) void gemm_kernel(
    const unsigned short* __restrict__ Fb, const unsigned short* __restrict__ Pb,
    const int* __restrict__ novel_idx, const int* __restrict__ counters,
    int M, int B,
    float* __restrict__ S1, float* __restrict__ T1,
    float* __restrict__ PKr, float* __restrict__ EK)
{
    __shared__ unsigned short As[128 * 128];   // 32 KiB, linear (swizzled chunks)
    __shared__ unsigned short Bs[128 * 128];   // 32 KiB
    __shared__ int nidx[128];

    const int Nn = counters[0];
    const int ntiles = (Nn + 127) >> 7;        // novel col tiles
    const int width = ntiles + 1;              // + proto tile
    const int rtc = (M + 127) >> 7;            // row tiles
    const long total = (long)rtc * width;
    const int G = gridDim.x, b = blockIdx.x;
    const int t0 = (int)(total * b / G);
    const int t1 = (int)(total * (b + 1) / G);
    if (t0 >= t1) return;

    const int tid = threadIdx.x;
    const int wbase = tid & ~63;               // wave-uniform thread base
    const int wave = tid >> 6, lane = tid & 63;
    const int lr = lane & 15, quad = lane >> 4;
    const int wrow = (wave >> 1) * 64, wcol = (wave & 1) * 64;

    float se16[4][4], sr16[4][4];
    int pend_row0 = -1;                        // -1 = no pending run
    bool pend_isp = false;
    int cur_rt = -1;
    bool first = true;

    for (int t = t0; t < t1; ++t) {
        const int rt = t / width, ct = t - rt * width;
        const bool isp = (ct == ntiles);
        const int row0 = rt * 128;

        if (isp != pend_isp || row0 != pend_row0) {    // block-uniform
            if (pend_row0 >= 0)
                flush_run(se16, sr16, pend_isp ? EK : S1, pend_isp ? PKr : T1,
                          pend_row0, wrow, quad, lr, M);
            #pragma unroll
            for (int r = 0; r < 4; ++r)
                #pragma unroll
                for (int g = 0; g < 4; ++g) { se16[r][g] = 0.f; sr16[r][g] = 0.f; }
            pend_isp = isp; pend_row0 = row0;
        }

        if (!first) __syncthreads();           // readers of prev tile done
        first = false;

        if (rt != cur_rt) {                    // stage A once per rt-run
            cur_rt = rt;
            const unsigned short* a0 = Fb + (size_t)row0 * KDIM;
            #pragma unroll
            for (int p = 0; p < 8; ++p) {
                int Lc = p * 256 + tid;
                int r = Lc >> 4, c = Lc & 15;
                int cs = c ^ (r & 15);         // source-side XOR swizzle
                g2lds16(a0 + (size_t)r * KDIM + cs * 8,
                        As + (size_t)(p * 256 + wbase) * 8);
            }
        }
        #pragma unroll
        for (int p = 0; p < 8; ++p) {          // stage B (gathered / protos)
            int Lc = p * 256 + tid;
            int r = Lc >> 4, c = Lc & 15;
            int cs = c ^ (r & 15);
            const unsigned short* base; int nid;
            if (isp) { base = Pb; nid = r; }              // Pb zero-padded
            else {
                base = Fb;
                int jg = ct * 128 + r;
                nid = (jg < Nn) ? novel_idx[jg] : M;      // M = zero row
            }
            g2lds16(base + (size_t)nid * KDIM + cs * 8,
                    Bs + (size_t)(p * 256 + wbase) * 8);
        }
        if (tid < 128) {
            int nid = -1;
            if (isp) { if (tid < B) nid = tid; }
            else { int jg = ct * 128 + tid; if (jg < Nn) nid = novel_idx[jg]; }
            nidx[tid] = nid;
        }
        __syncthreads();                       // drains vmcnt (async LDS loads)

        floatx4 acc[4][4];
        #pragma unroll
        for (int r = 0; r < 4; ++r)
            #pragma unroll
            for (int c = 0; c < 4; ++c)
                acc[r][c] = (floatx4){0.f, 0.f, 0.f, 0.f};

        #pragma unroll
        for (int ks = 0; ks < 4; ++ks) {       // swizzled ds_read_b128
            short8 a[4], bfr[4];
            #pragma unroll
            for (int r = 0; r < 4; ++r) {
                int row = wrow + r * 16 + lr;
                int phys = (ks * 4 + quad) ^ lr;
                a[r] = *(const short8*)&As[row * KDIM + phys * 8];
            }
            #pragma unroll
            for (int c = 0; c < 4; ++c) {
                int row = wcol + c * 16 + lr;
                int phys = (ks * 4 + quad) ^ lr;
                bfr[c] = *(const short8*)&Bs[row * KDIM + phys * 8];
            }
            #pragma unroll
            for (int r = 0; r < 4; ++r)
                #pragma unroll
                for (int c = 0; c < 4; ++c)
                    acc[r][c] = __builtin_amdgcn_mfma_f32_16x16x32_bf16(
                        a[r], bfr[c], acc[r][c], 0, 0, 0);
        }

        int ncol[4];
        #pragma unroll
        for (int c = 0; c < 4; ++c) ncol[c] = nidx[wcol + c * 16 + lr];
        #pragma unroll
        for (int r = 0; r < 4; ++r) {
            int ibase = row0 + wrow + r * 16 + quad * 4;
            #pragma unroll
            for (int reg = 0; reg < 4; ++reg) {
                int irow = ibase + reg;        // C/D: col=lane&15, row=quad*4+reg
                float se = 0.f, sr = 0.f;
                #pragma unroll
                for (int c = 0; c < 4; ++c) {
                    float sim = acc[r][c][reg] * INV_T;
                    bool valid = (ncol[c] >= 0) && (isp || ncol[c] != irow);
                    if (valid) { se += __expf(sim); sr += sim; }
                }
                se16[r][reg] += se;
                sr16[r][reg] += sr;
            }
        }
    }
    if (pend_row0 >= 0)
        flush_run(se16, sr16, pend_isp ? EK : S1, pend_isp ? PKr : T1,
                  pend_row0, wrow, quad, lr, M);
}

// ---------------- finalize: per-row losses (pi exact in fp32) -> scalar -------
__global__ __launch_bounds__(256) void finalize_kernel(
    const float* __restrict__ feats, const float* __restrict__ protos,
    const int* __restrict__ labels,
    const float* __restrict__ S1, const float* __restrict__ T1,
    const float* __restrict__ PKr, const float* __restrict__ EK,
    const int* __restrict__ counters, int M, int B, float* __restrict__ out)
{
    __shared__ float part[16];
    const int tid  = threadIdx.x;
    const int rloc = tid >> 4;
    const int q    = tid & 15;
    const int row  = blockIdx.x * 16 + rloc;
    const int rs   = min(row, M - 1);

    const int Nn = counters[0], numel = counters[1], nbase = counters[2];

    int lab = labels[rs];
    bool fg  = (lab != NCLS);
    bool isb = fg && (lab >= 0) && (lab < B);
    bool isn = fg && !isb;
    int  sl  = min(max(lab, 0), B - 1);

    // exact fp32 dot f_row . protos[sl] (16 lanes x 8 elems)
    float d = 0.f;
    #pragma unroll
    for (int j = 0; j < 8; ++j) {
        int k = q + j * 16;
        d += feats[(size_t)rs * KDIM + k] * protos[(size_t)sl * KDIM + k];
    }
    #pragma unroll
    for (int off = 1; off < 16; off <<= 1) d += __shfl_xor(d, off);

    if (q == 0) {
        float loss = 0.f;
        if (row < M) {
            if (isn && Nn > 1) {
                float cnt = (float)(Nn - 1);
                float dn  = S1[rs] + PKr[rs];
                loss = -(T1[rs] - cnt * logf(dn)) / cnt;
            } else if (isb && nbase > 0) {
                float pi = d * INV_T;
                float db = S1[rs] + EK[rs];
                loss = -(pi - logf(db));
            }
        }
        part[rloc] = loss;
    }
    __syncthreads();
    if (tid == 0) {
        float s = 0.f;
        #pragma unroll
        for (int r = 0; r < 16; ++r) s += part[r];
        atomicAdd(out, s / (float)numel);
    }
}

extern "C" void kernel_launch(void* const* d_in, const int* in_sizes, int n_in,
                              void* d_out, int out_size, void* d_ws, size_t ws_size,
                              hipStream_t stream)
{
    const float* feats  = (const float*)d_in[0];
    const int*   labels = (const int*)d_in[1];
    const float* protos = (const float*)d_in[2];
    // d_in[3] proto_labels == arange(B); base membership == (label < B)

    const int M = in_sizes[1];
    const int B = in_sizes[3];

    char* ws = (char*)d_ws;
    int*   counters = (int*)ws;                   // 16 ints
    float* S1  = (float*)(ws + 64);
    float* T1  = S1 + M;
    float* PKr = T1 + M;
    float* EK  = PKr + M;
    int*   novel_idx = (int*)(EK + M);            // M ints
    unsigned short* Fb = (unsigned short*)(novel_idx + M);   // (M+1) x 128 bf16
    unsigned short* Pb = Fb + (size_t)(M + 1) * KDIM;        // 128 x 128 bf16

    hipMemsetAsync(counters, 0, 64, stream);      // counters only

    setup_kernel<<<256, 256, 0, stream>>>(
        feats, labels, protos, M, B, novel_idx, counters,
        S1, T1, PKr, EK, (float*)d_out, Fb, Pb);

    gemm_kernel<<<512, 256, 0, stream>>>(
        Fb, Pb, novel_idx, counters, M, B, S1, T1, PKr, EK);

    finalize_kernel<<<(M + 15) / 16, 256, 0, stream>>>(
        feats, protos, labels, S1, T1, PKr, EK, counters, M, B, (float*)d_out);
}

// Round 4
// 98.329 us; speedup vs baseline: 1.4801x; 1.0080x over previous
//
#include <hip/hip_runtime.h>
#include <math.h>

#define NCLS 80           // background label
#define KDIM 128
#define INV_T 5.0f        // 1/TEMPERATURE

typedef __attribute__((ext_vector_type(4))) float  floatx4;
typedef __attribute__((ext_vector_type(8))) short  short8;

__device__ inline unsigned short f2bf(float x) {      // fp32 -> bf16 RNE
    unsigned int u = __float_as_uint(x);
    u += 0x7fffu + ((u >> 16) & 1u);
    return (unsigned short)(u >> 16);
}
__device__ inline short8 pack8(float4 a, float4 b) {
    short8 o;
    o[0] = (short)f2bf(a.x); o[1] = (short)f2bf(a.y);
    o[2] = (short)f2bf(a.z); o[3] = (short)f2bf(a.w);
    o[4] = (short)f2bf(b.x); o[5] = (short)f2bf(b.y);
    o[6] = (short)f2bf(b.z); o[7] = (short)f2bf(b.w);
    return o;
}
// async 16B global->LDS; LDS dest is wave-uniform base + lane*16
__device__ inline void g2lds16(const void* g, void* l) {
    __builtin_amdgcn_global_load_lds(
        (const __attribute__((address_space(1))) void*)g,
        (__attribute__((address_space(3))) void*)l, 16, 0, 0);
}

// ---------------- setup: compact novel indices, counts, zero accumulators,
// convert feats -> bf16 (Fb, + zero row M), protos -> bf16 (Pb, padded to 128).
// 512 blocks: one 16B chunk per thread; contiguous float4 zeroing sweep. -----
__global__ __launch_bounds__(256) void setup_kernel(
    const float* __restrict__ feats, const int* __restrict__ labels,
    const float* __restrict__ protos, int M, int B,
    int* __restrict__ novel_idx, int* __restrict__ counters,
    float* __restrict__ accz,      // S1|T1|PKr|EK contiguous, 4*M floats
    float* __restrict__ out,
    unsigned short* __restrict__ Fb, unsigned short* __restrict__ Pb)
{
    const int i = blockIdx.x * 256 + threadIdx.x;
    const int T = gridDim.x * 256;             // 131072
    if (i == 0) out[0] = 0.f;
    if (i < M) {
        int lab = labels[i];
        bool fg  = (lab != NCLS);
        bool isb = fg && (lab >= 0) && (lab < B);
        bool isn = fg && !isb;
        if (isn) { int p = atomicAdd(&counters[0], 1); novel_idx[p] = i; }
        if (fg)  atomicAdd(&counters[1], 1);   // numel
        if (isb) atomicAdd(&counters[2], 1);   // n_base
    }
    // zero the 4 contiguous accumulator arrays: M float4 chunks
    if (i < M) *((float4*)accz + i) = make_float4(0.f, 0.f, 0.f, 0.f);

    // feats -> bf16 rows 0..M-1, plus zero row M (gather target for invalid cols)
    const int nch = (M + 1) * (KDIM / 8);      // 16-byte chunks (131088)
    for (int ch = i; ch < nch; ch += T) {
        short8 o = (short8)0;
        if (ch < M * (KDIM / 8)) {
            const float4* f4 = (const float4*)feats + (size_t)ch * 2;
            o = pack8(f4[0], f4[1]);
        }
        *(short8*)&Fb[(size_t)ch * 8] = o;
    }
    // protos -> bf16, zero-padded to 128 rows
    if (i < 128 * (KDIM / 8)) {
        int r = i >> 4;
        short8 o = (short8)0;
        if (r < B) {
            const float4* p4 = (const float4*)protos + (size_t)i * 2;
            o = pack8(p4[0], p4[1]);
        }
        *(short8*)&Pb[(size_t)i * 8] = o;
    }
}

// ---- shuffle-reduce + atomic flush of a run's (exp-sum, raw-sum) pairs ------
__device__ inline void flush_run(float se16[4][4], float sr16[4][4],
                                 float* dE, float* dR, int row0,
                                 int wrow, int quad, int lr, int M)
{
    #pragma unroll
    for (int r = 0; r < 4; ++r) {
        #pragma unroll
        for (int reg = 0; reg < 4; ++reg) {
            float ve = se16[r][reg], vr = sr16[r][reg];
            #pragma unroll
            for (int off = 1; off < 16; off <<= 1) {
                ve += __shfl_xor(ve, off);
                vr += __shfl_xor(vr, off);
            }
            if (lr == 0) {
                int irow = row0 + wrow + r * 16 + quad * 4 + reg;
                if (irow < M) { atomicAdd(&dE[irow], ve); atomicAdd(&dR[irow], vr); }
            }
        }
    }
}

// ---------------- MFMA GEMM: exp-sums and raw-sums over novel/proto cols -----
// Balanced device-side partition of the rt-major tile list (width = ntiles+1)
// over a fixed grid; A panel staged once per rt-run; epilogue accumulates
// per-lane (se,sr) across the run and flushes once per destination run.
__global__ __launch_bounds__(256, 2) void gemm_kernel(
    const unsigned short* __restrict__ Fb, const unsigned short* __restrict__ Pb,
    const int* __restrict__ novel_idx, const int* __restrict__ counters,
    int M, int B,
    float* __restrict__ S1, float* __restrict__ T1,
    float* __restrict__ PKr, float* __restrict__ EK)
{
    __shared__ unsigned short As[128 * 128];   // 32 KiB, linear (swizzled chunks)
    __shared__ unsigned short Bs[128 * 128];   // 32 KiB
    __shared__ int nidx[128];

    const int Nn = counters[0];
    const int ntiles = (Nn + 127) >> 7;        // novel col tiles
    const int width = ntiles + 1;              // + proto tile
    const int rtc = (M + 127) >> 7;            // row tiles
    const long total = (long)rtc * width;
    const int G = gridDim.x, b = blockIdx.x;
    const int t0 = (int)(total * b / G);
    const int t1 = (int)(total * (b + 1) / G);
    if (t0 >= t1) return;

    const int tid = threadIdx.x;
    const int wbase = tid & ~63;               // wave-uniform thread base
    const int wave = tid >> 6, lane = tid & 63;
    const int lr = lane & 15, quad = lane >> 4;
    const int wrow = (wave >> 1) * 64, wcol = (wave & 1) * 64;

    float se16[4][4], sr16[4][4];
    int pend_row0 = -1;                        // -1 = no pending run
    bool pend_isp = false;
    int cur_rt = -1;
    bool first = true;

    for (int t = t0; t < t1; ++t) {
        const int rt = t / width, ct = t - rt * width;
        const bool isp = (ct == ntiles);
        const int row0 = rt * 128;

        if (isp != pend_isp || row0 != pend_row0) {    // block-uniform
            if (pend_row0 >= 0)
                flush_run(se16, sr16, pend_isp ? EK : S1, pend_isp ? PKr : T1,
                          pend_row0, wrow, quad, lr, M);
            #pragma unroll
            for (int r = 0; r < 4; ++r)
                #pragma unroll
                for (int g = 0; g < 4; ++g) { se16[r][g] = 0.f; sr16[r][g] = 0.f; }
            pend_isp = isp; pend_row0 = row0;
        }

        if (!first) __syncthreads();           // readers of prev tile done
        first = false;

        if (rt != cur_rt) {                    // stage A once per rt-run
            cur_rt = rt;
            const unsigned short* a0 = Fb + (size_t)row0 * KDIM;
            #pragma unroll
            for (int p = 0; p < 8; ++p) {
                int Lc = p * 256 + tid;
                int r = Lc >> 4, c = Lc & 15;
                int cs = c ^ (r & 15);         // source-side XOR swizzle
                g2lds16(a0 + (size_t)r * KDIM + cs * 8,
                        As + (size_t)(p * 256 + wbase) * 8);
            }
        }
        #pragma unroll
        for (int p = 0; p < 8; ++p) {          // stage B (gathered / protos)
            int Lc = p * 256 + tid;
            int r = Lc >> 4, c = Lc & 15;
            int cs = c ^ (r & 15);
            const unsigned short* base; int nid;
            if (isp) { base = Pb; nid = r; }              // Pb zero-padded
            else {
                base = Fb;
                int jg = ct * 128 + r;
                nid = (jg < Nn) ? novel_idx[jg] : M;      // M = zero row
            }
            g2lds16(base + (size_t)nid * KDIM + cs * 8,
                    Bs + (size_t)(p * 256 + wbase) * 8);
        }
        if (tid < 128) {
            int nid = -1;
            if (isp) { if (tid < B) nid = tid; }
            else { int jg = ct * 128 + tid; if (jg < Nn) nid = novel_idx[jg]; }
            nidx[tid] = nid;
        }
        __syncthreads();                       // drains vmcnt (async LDS loads)

        floatx4 acc[4][4];
        #pragma unroll
        for (int r = 0; r < 4; ++r)
            #pragma unroll
            for (int c = 0; c < 4; ++c)
                acc[r][c] = (floatx4){0.f, 0.f, 0.f, 0.f};

        #pragma unroll
        for (int ks = 0; ks < 4; ++ks) {       // swizzled ds_read_b128
            short8 a[4], bfr[4];
            #pragma unroll
            for (int r = 0; r < 4; ++r) {
                int row = wrow + r * 16 + lr;
                int phys = (ks * 4 + quad) ^ lr;
                a[r] = *(const short8*)&As[row * KDIM + phys * 8];
            }
            #pragma unroll
            for (int c = 0; c < 4; ++c) {
                int row = wcol + c * 16 + lr;
                int phys = (ks * 4 + quad) ^ lr;
                bfr[c] = *(const short8*)&Bs[row * KDIM + phys * 8];
            }
            #pragma unroll
            for (int r = 0; r < 4; ++r)
                #pragma unroll
                for (int c = 0; c < 4; ++c)
                    acc[r][c] = __builtin_amdgcn_mfma_f32_16x16x32_bf16(
                        a[r], bfr[c], acc[r][c], 0, 0, 0);
        }

        int ncol[4];
        #pragma unroll
        for (int c = 0; c < 4; ++c) ncol[c] = nidx[wcol + c * 16 + lr];
        #pragma unroll
        for (int r = 0; r < 4; ++r) {
            int ibase = row0 + wrow + r * 16 + quad * 4;
            #pragma unroll
            for (int reg = 0; reg < 4; ++reg) {
                int irow = ibase + reg;        // C/D: col=lane&15, row=quad*4+reg
                float se = 0.f, sr = 0.f;
                #pragma unroll
                for (int c = 0; c < 4; ++c) {
                    float sim = acc[r][c][reg] * INV_T;
                    bool valid = (ncol[c] >= 0) && (isp || ncol[c] != irow);
                    if (valid) { se += __expf(sim); sr += sim; }
                }
                se16[r][reg] += se;
                sr16[r][reg] += sr;
            }
        }
    }
    if (pend_row0 >= 0)
        flush_run(se16, sr16, pend_isp ? EK : S1, pend_isp ? PKr : T1,
                  pend_row0, wrow, quad, lr, M);
}

// ---------------- finalize: per-row losses (pi exact in fp32) -> scalar -------
// 16 lanes/row, contiguous 8-float chunk per lane (float4 loads).
__global__ __launch_bounds__(256) void finalize_kernel(
    const float* __restrict__ feats, const float* __restrict__ protos,
    const int* __restrict__ labels,
    const float* __restrict__ S1, const float* __restrict__ T1,
    const float* __restrict__ PKr, const float* __restrict__ EK,
    const int* __restrict__ counters, int M, int B, float* __restrict__ out)
{
    __shared__ float part[16];
    const int tid  = threadIdx.x;
    const int rloc = tid >> 4;
    const int q    = tid & 15;
    const int row  = blockIdx.x * 16 + rloc;
    const int rs   = min(row, M - 1);

    const int Nn = counters[0], numel = counters[1], nbase = counters[2];

    int lab = labels[rs];
    bool fg  = (lab != NCLS);
    bool isb = fg && (lab >= 0) && (lab < B);
    bool isn = fg && !isb;
    int  sl  = min(max(lab, 0), B - 1);

    // fp32 dot f_row . protos[sl]: lane q owns elements [q*8, q*8+8)
    const float4* f4 = (const float4*)(feats  + (size_t)rs * KDIM) + q * 2;
    const float4* p4 = (const float4*)(protos + (size_t)sl * KDIM) + q * 2;
    float4 a0 = f4[0], a1 = f4[1];
    float4 b0 = p4[0], b1 = p4[1];
    float d = a0.x * b0.x + a0.y * b0.y + a0.z * b0.z + a0.w * b0.w
            + a1.x * b1.x + a1.y * b1.y + a1.z * b1.z + a1.w * b1.w;
    #pragma unroll
    for (int off = 1; off < 16; off <<= 1) d += __shfl_xor(d, off);

    if (q == 0) {
        float loss = 0.f;
        if (row < M) {
            if (isn && Nn > 1) {
                float cnt = (float)(Nn - 1);
                float dn  = S1[rs] + PKr[rs];
                loss = -(T1[rs] - cnt * logf(dn)) / cnt;
            } else if (isb && nbase > 0) {
                float pi = d * INV_T;
                float db = S1[rs] + EK[rs];
                loss = -(pi - logf(db));
            }
        }
        part[rloc] = loss;
    }
    __syncthreads();
    if (tid == 0) {
        float s = 0.f;
        #pragma unroll
        for (int r = 0; r < 16; ++r) s += part[r];
        atomicAdd(out, s / (float)numel);
    }
}

extern "C" void kernel_launch(void* const* d_in, const int* in_sizes, int n_in,
                              void* d_out, int out_size, void* d_ws, size_t ws_size,
                              hipStream_t stream)
{
    const float* feats  = (const float*)d_in[0];
    const int*   labels = (const int*)d_in[1];
    const float* protos = (const float*)d_in[2];
    // d_in[3] proto_labels == arange(B); base membership == (label < B)

    const int M = in_sizes[1];
    const int B = in_sizes[3];

    char* ws = (char*)d_ws;
    int*   counters = (int*)ws;                   // 16 ints
    float* S1  = (float*)(ws + 64);               // S1|T1|PKr|EK contiguous
    float* T1  = S1 + M;
    float* PKr = T1 + M;
    float* EK  = PKr + M;
    int*   novel_idx = (int*)(EK + M);            // M ints
    unsigned short* Fb = (unsigned short*)(novel_idx + M);   // (M+1) x 128 bf16
    unsigned short* Pb = Fb + (size_t)(M + 1) * KDIM;        // 128 x 128 bf16

    hipMemsetAsync(counters, 0, 64, stream);      // counters only

    setup_kernel<<<512, 256, 0, stream>>>(
        feats, labels, protos, M, B, novel_idx, counters,
        S1, (float*)d_out, Fb, Pb);

    gemm_kernel<<<512, 256, 0, stream>>>(
        Fb, Pb, novel_idx, counters, M, B, S1, T1, PKr, EK);

    finalize_kernel<<<(M + 15) / 16, 256, 0, stream>>>(
        feats, protos, labels, S1, T1, PKr, EK, counters, M, B, (float*)d_out);
}